// Round 5
// baseline (1894.102 us; speedup 1.0000x reference)
//
#include <hip/hip_runtime.h>
#include <cstdint>
#include <cstddef>

// ---------------------------------------------------------------------------
// MoE RQ-VAE forward.
//   Encoder: f16 two-term split MFMA (3 products) -> fp32-grade z.
//            Big layers: 128x256 tile, 8 waves, NBUF=3, register-level
//            fragment double-buffer: MFMA on tile it (regs) overlaps the
//            ds_read prefetch of tile it+1 and the gload staging of it+2.
//   RQ: rows sorted by expert; fused MFMA score+argmin+fp32 residual update.
//   Decoder: plain bf16 MFMA on the same schedule.
//   Tiny layers (enc L3, dec d0) keep the 128-row 4-wave pipelined kernel.
// ---------------------------------------------------------------------------

typedef _Float16 half8  __attribute__((ext_vector_type(8)));
typedef short    short8 __attribute__((ext_vector_type(8)));
typedef float    f32x4  __attribute__((ext_vector_type(4)));

__device__ __forceinline__ uint16_t f32_to_bf16(float v) {
    uint32_t u = __float_as_uint(v);
    u += 0x7fff + ((u >> 16) & 1);
    return (uint16_t)(u >> 16);
}
__device__ __forceinline__ uint16_t f32_to_f16_bits(float v) {
    _Float16 h = (_Float16)v;
    return __builtin_bit_cast(uint16_t, h);
}
__device__ __forceinline__ void split16(float v, uint16_t& hb, uint16_t& lb) {
    hb = f32_to_f16_bits(v);
    float hf = (float)__builtin_bit_cast(_Float16, hb);
    lb = f32_to_f16_bits((v - hf) * 2048.0f);
}

__device__ __forceinline__ float wave_sum(float v) {
    #pragma unroll
    for (int off = 32; off > 0; off >>= 1)
        v += __shfl_xor(v, off, 64);
    return v;
}

#define GLOAD_LDS16(g, l)                                                      \
    __builtin_amdgcn_global_load_lds(                                          \
        (const __attribute__((address_space(1))) void*)(g),                    \
        (__attribute__((address_space(3))) void*)(l), 16, 0, 0)

// counted waitcnt helpers
__device__ __forceinline__ void wait_vm(int nf) {
    if (nf >= 12)     asm volatile("s_waitcnt vmcnt(12)" ::: "memory");
    else if (nf >= 8) asm volatile("s_waitcnt vmcnt(8)"  ::: "memory");
    else if (nf >= 6) asm volatile("s_waitcnt vmcnt(6)"  ::: "memory");
    else if (nf >= 4) asm volatile("s_waitcnt vmcnt(4)"  ::: "memory");
    else              asm volatile("s_waitcnt vmcnt(0)"  ::: "memory");
}
template<int N>
__device__ __forceinline__ void wait_vmK() {
    if constexpr (N == 3)      asm volatile("s_waitcnt vmcnt(3)" ::: "memory");
    else if constexpr (N == 6) asm volatile("s_waitcnt vmcnt(6)" ::: "memory");
    else                       asm volatile("s_waitcnt vmcnt(0)" ::: "memory");
}
__device__ __forceinline__ void wait_lg0() { asm volatile("s_waitcnt lgkmcnt(0)" ::: "memory"); }

template<bool F16> struct VecT        { using type = half8;  };
template<>         struct VecT<false> { using type = short8; };

__device__ __forceinline__ f32x4 mfma16(half8 a, half8 b, f32x4 c) {
    return __builtin_amdgcn_mfma_f32_16x16x32_f16(a, b, c, 0, 0, 0);
}
__device__ __forceinline__ f32x4 mfma16(short8 a, short8 b, f32x4 c) {
    return __builtin_amdgcn_mfma_f32_16x16x32_bf16(a, b, c, 0, 0, 0);
}

// ---------------------------------------------------------------------------
// Wide-tile GEMM: C[M,N] = act(A[M,K] @ W[K,N] + bias)
// BM=128, BN=256, 512 threads (8 waves, 2M x 4N), wave tile 64x64.
// NBUF=3 LDS buffers + register fragment double-buffer:
//   step it: { stage(it+2) | [CORR: read lo-frags(it)] | MFMA grp1 on regs |
//              vmcnt(LPS) -> read hi-frags(it+1) into other reg set |
//              [CORR: MFMA grp2,grp3] | lgkm0 -> barrier }
// The MFMAs never depend on this step's ds_reads -> LDS and matrix pipes
// overlap. Lifecycle: vmcnt(LPS) mid-region certifies tile it+1 resident
// (only it+2's LPS loads outstanding); seam lgkm0+barrier certifies all
// reads of a buffer done one full step before it is restaged.
// nt = K/32 must be even and >= 4 (true for all layer shapes).
// ---------------------------------------------------------------------------
template<bool ISF16, bool CORR, bool RELU, int OUT>
__global__ __launch_bounds__(512, 2)
void gemm_256(const uint16_t* __restrict__ A, const uint16_t* __restrict__ Wt,
              const float* __restrict__ bias,
              float* __restrict__ Cf, uint16_t* __restrict__ C0,
              uint16_t* __restrict__ C1, int M, int K, int N) {
    using vec8 = typename VecT<ISF16>::type;
    constexpr int NPL    = CORR ? 2 : 1;
    constexpr int ABYT   = 8192;                 // 128 rows x 32k x 2B per plane
    constexpr int BBYT   = 16384;                // 256 rows x 32k x 2B per plane
    constexpr int TILE_B = NPL * (ABYT + BBYT);  // 49152 | 24576
    constexpr int NBUF   = 3;
    constexpr int LPS    = CORR ? 6 : 3;         // gloads per thread per K-step
    __shared__ __align__(16) char lds[NBUF * TILE_B];

    const int t    = threadIdx.x;
    const int lane = t & 63, wave = t >> 6;      // 8 waves
    const int wm = wave >> 2, wn = wave & 3;
    const int bm = blockIdx.y, bn = blockIdx.x;

    const size_t planeA = (size_t)M * K;
    const size_t planeB = (size_t)N * K;

    // staging source: thread t covers row r, xor-swizzled 16B chunk c
    const int r = t >> 2;
    const int c = (t & 3) ^ ((r >> 1) & 3);
    const uint16_t* gA  = A  + (size_t)(bm * 128 + r) * K + c * 8;
    const uint16_t* gB0 = Wt + (size_t)(bn * 256 + r) * K + c * 8;
    const uint16_t* gB1 = Wt + (size_t)(bn * 256 + 128 + r) * K + c * 8;

    const int l15 = lane & 15, quad = lane >> 4;
    const int cpf = quad ^ ((l15 >> 1) & 3);
    const int aoff = ((wm * 64 + l15) * 4 + cpf) * 16;
    const int boff = ((wn * 64 + l15) * 4 + cpf) * 16;

    f32x4 accM[4][4], accC[4][4];
    #pragma unroll
    for (int mi = 0; mi < 4; ++mi)
        #pragma unroll
        for (int nj = 0; nj < 4; ++nj)
            #pragma unroll
            for (int rr = 0; rr < 4; ++rr) { accM[mi][nj][rr] = 0.f; if (CORR) accC[mi][nj][rr] = 0.f; }

    const int nt = K >> 5;                       // even, >= 4

    auto stageA = [&](int ti, int bi) {          // A hi (+lo): 1|2 loads
        char* b = (char*)lds + bi * TILE_B;
        const int kb = ti * 32;
        GLOAD_LDS16(gA + kb, b + t * 16);
        if (CORR) GLOAD_LDS16(gA + planeA + kb, b + ABYT + t * 16);
    };
    auto stageBh = [&](int ti, int bi) {         // B hi: 2 loads
        char* b = (char*)lds + bi * TILE_B + NPL * ABYT;
        const int kb = ti * 32;
        GLOAD_LDS16(gB0 + kb, b + t * 16);
        GLOAD_LDS16(gB1 + kb, b + 8192 + t * 16);
    };
    auto stageBl = [&](int ti, int bi) {         // B lo: 2 loads (CORR only)
        char* b = (char*)lds + bi * TILE_B + NPL * ABYT + BBYT;
        const int kb = ti * 32;
        GLOAD_LDS16(gB0 + planeB + kb, b + t * 16);
        GLOAD_LDS16(gB1 + planeB + kb, b + 8192 + t * 16);
    };

    // prologue: tiles 0 and 1 in flight
    stageA(0, 0); stageBh(0, 0); if (CORR) stageBl(0, 0);
    stageA(1, 1); stageBh(1, 1); if (CORR) stageBl(1, 1);
    wait_vmK<LPS>();                             // tile 0 resident
    __builtin_amdgcn_sched_barrier(0);
    __builtin_amdgcn_s_barrier();

    // hi-fragment register double-buffer
    vec8 a0A[4], b0A[4], a0B[4], b0B[4];
    #pragma unroll
    for (int i = 0; i < 4; ++i) {
        a0A[i] = *(const vec8*)((char*)lds + aoff + i * 1024);
        b0A[i] = *(const vec8*)((char*)lds + NPL * ABYT + boff + i * 1024);
    }

    auto step = [&](int it, int cur, vec8 (&a0c)[4], vec8 (&b0c)[4],
                    vec8 (&a0n)[4], vec8 (&b0n)[4]) {
        char* bufc = (char*)lds + cur * TILE_B;
        int nb_ = cur + 1; if (nb_ == NBUF) nb_ = 0;
        char* bufn = (char*)lds + nb_ * TILE_B;
        int bi = cur + 2; if (bi >= NBUF) bi -= NBUF;
        const int nx = it + 2;
        const bool st = nx < nt;
        const bool rd = it + 1 < nt;

        // issue staging for tile it+2 (its buffer's readers certified at the
        // seam of step it-1)
        if (st) { stageA(nx, bi); stageBh(nx, bi); if (CORR) stageBl(nx, bi); }

        // current-tile lo fragments (CORR): consumed by groups 2/3 below;
        // group 1 covers their LDS latency.
        vec8 b1c[4], a1c[4];
        if (CORR) {
            #pragma unroll
            for (int i = 0; i < 4; ++i) {
                b1c[i] = *(const vec8*)(bufc + NPL * ABYT + BBYT + boff + i * 1024);
                a1c[i] = *(const vec8*)(bufc + ABYT + aoff + i * 1024);
            }
        }

        // group 1: operands already in registers -> no lgkm dependency
        #pragma unroll
        for (int mi = 0; mi < 4; ++mi)
            #pragma unroll
            for (int nj = 0; nj < 4; ++nj)
                accM[mi][nj] = mfma16(a0c[mi], b0c[nj], accM[mi][nj]);

        // prefetch next tile's hi fragments into the other register set
        if (rd) {
            if (st) wait_vmK<LPS>(); else wait_vmK<0>();   // tile it+1 resident
            #pragma unroll
            for (int i = 0; i < 4; ++i) {
                a0n[i] = *(const vec8*)(bufn + aoff + i * 1024);
                b0n[i] = *(const vec8*)(bufn + NPL * ABYT + boff + i * 1024);
            }
        }

        if (CORR) {
            #pragma unroll
            for (int mi = 0; mi < 4; ++mi)
                #pragma unroll
                for (int nj = 0; nj < 4; ++nj)
                    accC[mi][nj] = mfma16(a0c[mi], b1c[nj], accC[mi][nj]);
            #pragma unroll
            for (int mi = 0; mi < 4; ++mi)
                #pragma unroll
                for (int nj = 0; nj < 4; ++nj)
                    accC[mi][nj] = mfma16(a1c[mi], b0c[nj], accC[mi][nj]);
        }

        // seam: all my LDS reads landed; one barrier per K-step
        if (rd) {
            wait_lg0();
            __builtin_amdgcn_sched_barrier(0);
            __builtin_amdgcn_s_barrier();
            __builtin_amdgcn_sched_barrier(0);
        }
    };

    int cur = 0;
    for (int it = 0; it < nt; it += 2) {
        step(it, cur, a0A, b0A, a0B, b0B);
        int cur1 = cur + 1; if (cur1 == NBUF) cur1 = 0;
        step(it + 1, cur1, a0B, b0B, a0A, b0A);
        cur = cur1 + 1; if (cur == NBUF) cur = 0;
    }

    if (CORR) {
        #pragma unroll
        for (int mi = 0; mi < 4; ++mi)
            #pragma unroll
            for (int nj = 0; nj < 4; ++nj)
                #pragma unroll
                for (int rr = 0; rr < 4; ++rr)
                    accM[mi][nj][rr] += accC[mi][nj][rr] * (1.0f / 2048.0f);
    }

    const int colb = bn * 256 + wn * 64 + l15;
    const int rowb = bm * 128 + wm * 64 + quad * 4;
    float bz[4];
    #pragma unroll
    for (int nj = 0; nj < 4; ++nj) bz[nj] = bias[colb + nj * 16];

    #pragma unroll
    for (int mi = 0; mi < 4; ++mi)
        #pragma unroll
        for (int nj = 0; nj < 4; ++nj)
            #pragma unroll
            for (int rr = 0; rr < 4; ++rr) {
                float v = accM[mi][nj][rr] + bz[nj];
                if (RELU) v = fmaxf(v, 0.f);
                const size_t o = (size_t)(rowb + mi * 16 + rr) * N + colb + nj * 16;
                if (OUT == 0) {
                    Cf[o] = v;
                } else if (OUT == 1) {
                    uint16_t hb, lb; split16(v, hb, lb);
                    C0[o] = hb; C1[o] = lb;
                } else {
                    C0[o] = f32_to_bf16(v);
                }
            }
}

// ---------------------------------------------------------------------------
// 128-row 4-wave pipelined GEMM for tiny layers (2 barriers per K-step).
// ---------------------------------------------------------------------------
template<int NPL, int NBUF, int BN, bool ISF16, bool CORR, bool RELU, int OUT>
__global__ __launch_bounds__(256)
void gemm_mfma(const uint16_t* __restrict__ A, const uint16_t* __restrict__ Wt,
               const float* __restrict__ bias,
               float* __restrict__ Cf, uint16_t* __restrict__ C0,
               uint16_t* __restrict__ C1, int M, int K, int N) {
    using vec8 = typename VecT<ISF16>::type;
    constexpr int APL    = 8192;
    constexpr int BPL    = BN * 64;
    constexpr int TILE_B = NPL * (APL + BPL);
    constexpr int BSHOT  = BN / 64;
    constexpr int NR     = BN / 32;
    constexpr int LPT    = NPL * (2 + BSHOT);
    __shared__ __align__(16) char lds[NBUF * TILE_B];

    const int t    = threadIdx.x;
    const int lane = t & 63, wave = t >> 6;
    const int wm = wave >> 1, wn = wave & 1;
    const int bm = blockIdx.y, bn = blockIdx.x;

    const size_t planeA = (size_t)M * K;
    const size_t planeB = (size_t)N * K;

    const int r0 = t >> 2,        c0 = (t & 3) ^ ((r0 >> 1) & 3);
    const int r1 = 64 + (t >> 2), c1 = (t & 3) ^ ((r1 >> 1) & 3);

    const uint16_t* gA0 = A + (size_t)(bm * 128 + r0) * K + c0 * 8;
    const uint16_t* gA1 = A + (size_t)(bm * 128 + r1) * K + c1 * 8;
    const uint16_t* gB[2];
    gB[0] = Wt + (size_t)(bn * BN + r0) * K + c0 * 8;
    if (BSHOT == 2) gB[1] = Wt + (size_t)(bn * BN + r1) * K + c1 * 8;

    const int wb = wave * 1024;
    const int l15 = lane & 15, quad = lane >> 4;
    const int cpf = quad ^ ((l15 >> 1) & 3);
    const int aoff = ((wm * 64 + l15) * 4 + cpf) * 16;
    const int boff = ((wn * (BN / 2) + l15) * 4 + cpf) * 16;

    f32x4 accM[4][NR], accC[4][NR];
    #pragma unroll
    for (int mi = 0; mi < 4; ++mi)
        #pragma unroll
        for (int nj = 0; nj < NR; ++nj)
            #pragma unroll
            for (int r = 0; r < 4; ++r) { accM[mi][nj][r] = 0.f; if (CORR) accC[mi][nj][r] = 0.f; }

    const int nt = K >> 5;

    auto stage = [&](int ti, int bi) {
        char* bA = (char*)lds + bi * TILE_B;
        char* bB = bA + NPL * APL;
        const int kb = ti * 32;
        #pragma unroll
        for (int p = 0; p < NPL; ++p) {
            GLOAD_LDS16(gA0 + (size_t)p * planeA + kb, bA + p * APL + wb);
            GLOAD_LDS16(gA1 + (size_t)p * planeA + kb, bA + p * APL + 4096 + wb);
            #pragma unroll
            for (int s = 0; s < BSHOT; ++s)
                GLOAD_LDS16(gB[s] + (size_t)p * planeB + kb, bB + p * BPL + s * 4096 + wb);
        }
    };

    #pragma unroll
    for (int i = 0; i < NBUF - 1; ++i) stage(i, i);

    int cur = 0;
    for (int it = 0; it < nt; ++it) {
        const int nx = it + NBUF - 1;
        if (nx < nt) {
            int bi = cur + NBUF - 1; if (bi >= NBUF) bi -= NBUF;
            stage(nx, bi);
        }
        const int rem = nt - 1 - it;
        const int nf  = (rem < NBUF - 1 ? rem : NBUF - 1) * LPT;
        wait_vm(nf);
        __builtin_amdgcn_sched_barrier(0);
        __builtin_amdgcn_s_barrier();
        __builtin_amdgcn_sched_barrier(0);

        char* bA = (char*)lds + cur * TILE_B;
        char* bB = bA + NPL * APL;

        vec8 a0[4], b0[NR];
        #pragma unroll
        for (int i = 0; i < 4; ++i)
            a0[i] = *(const vec8*)(bA + aoff + i * 1024);
        #pragma unroll
        for (int i = 0; i < NR; ++i)
            b0[i] = *(const vec8*)(bB + boff + i * 1024);
        #pragma unroll
        for (int mi = 0; mi < 4; ++mi)
            #pragma unroll
            for (int nj = 0; nj < NR; ++nj)
                accM[mi][nj] = mfma16(a0[mi], b0[nj], accM[mi][nj]);

        if (CORR) {
            vec8 b1[NR];
            #pragma unroll
            for (int i = 0; i < NR; ++i)
                b1[i] = *(const vec8*)(bB + BPL + boff + i * 1024);
            #pragma unroll
            for (int mi = 0; mi < 4; ++mi)
                #pragma unroll
                for (int nj = 0; nj < NR; ++nj)
                    accC[mi][nj] = mfma16(a0[mi], b1[nj], accC[mi][nj]);
            vec8 a1[4];
            #pragma unroll
            for (int i = 0; i < 4; ++i)
                a1[i] = *(const vec8*)(bA + APL + aoff + i * 1024);
            #pragma unroll
            for (int mi = 0; mi < 4; ++mi)
                #pragma unroll
                for (int nj = 0; nj < NR; ++nj)
                    accC[mi][nj] = mfma16(a1[mi], b0[nj], accC[mi][nj]);
        }

        wait_lg0();
        __builtin_amdgcn_sched_barrier(0);
        __builtin_amdgcn_s_barrier();
        __builtin_amdgcn_sched_barrier(0);

        cur = cur + 1; if (cur == NBUF) cur = 0;
    }

    if (CORR) {
        #pragma unroll
        for (int mi = 0; mi < 4; ++mi)
            #pragma unroll
            for (int nj = 0; nj < NR; ++nj)
                #pragma unroll
                for (int r = 0; r < 4; ++r)
                    accM[mi][nj][r] += accC[mi][nj][r] * (1.0f / 2048.0f);
    }

    const int colb = bn * BN + wn * (BN / 2) + l15;
    const int rowb = bm * 128 + wm * 64 + quad * 4;
    float bz[NR];
    #pragma unroll
    for (int nj = 0; nj < NR; ++nj) bz[nj] = bias[colb + nj * 16];

    #pragma unroll
    for (int mi = 0; mi < 4; ++mi)
        #pragma unroll
        for (int nj = 0; nj < NR; ++nj)
            #pragma unroll
            for (int r = 0; r < 4; ++r) {
                float v = accM[mi][nj][r] + bz[nj];
                if (RELU) v = fmaxf(v, 0.f);
                const size_t o = (size_t)(rowb + mi * 16 + r) * N + colb + nj * 16;
                if (OUT == 0) {
                    Cf[o] = v;
                } else if (OUT == 1) {
                    uint16_t hb, lb; split16(v, hb, lb);
                    C0[o] = hb; C1[o] = lb;
                } else {
                    C0[o] = f32_to_bf16(v);
                }
            }
}

// ---------------------------------------------------------------------------
// Weight prep (unchanged)
// ---------------------------------------------------------------------------
template<int MODE>
__global__ __launch_bounds__(256)
void prep_w(const float* __restrict__ W, uint16_t* __restrict__ out, int K, int N) {
    __shared__ float tile[32][33];
    const int tx = threadIdx.x & 31, ty = threadIdx.x >> 5;
    const int n0 = blockIdx.x * 32, k0 = blockIdx.y * 32;
    #pragma unroll
    for (int i = 0; i < 4; ++i)
        tile[ty + i * 8][tx] = W[(size_t)(k0 + ty + i * 8) * N + n0 + tx];
    __syncthreads();
    #pragma unroll
    for (int i = 0; i < 4; ++i) {
        float v = tile[tx][ty + i * 8];
        size_t o = (size_t)(n0 + ty + i * 8) * K + k0 + tx;
        if (MODE == 0) {
            uint16_t hb, lb; split16(v, hb, lb);
            out[o] = hb;
            out[o + (size_t)N * K] = lb;
        } else {
            out[o] = f32_to_bf16(v);
        }
    }
}

__global__ __launch_bounds__(256)
void split_x(const float* __restrict__ x, uint16_t* __restrict__ hi,
             uint16_t* __restrict__ lo, int n4) {
    int i = blockIdx.x * 256 + threadIdx.x;
    const int stride = gridDim.x * 256;
    for (; i < n4; i += stride) {
        float4 v = ((const float4*)x)[i];
        ushort4 h, l;
        split16(v.x, h.x, l.x); split16(v.y, h.y, l.y);
        split16(v.z, h.z, l.z); split16(v.w, h.w, l.w);
        ((ushort4*)hi)[i] = h;
        ((ushort4*)lo)[i] = l;
    }
}

// ---------------------------------------------------------------------------
// Codebook prep: f16 hi/lo planes [l][e][k][d] + cnorm. One wave per row.
// ---------------------------------------------------------------------------
__global__ __launch_bounds__(256)
void prep_cb2(const float* __restrict__ cb, uint16_t* __restrict__ cbh,
              uint16_t* __restrict__ cbl, float* __restrict__ cnorm) {
    const int t = threadIdx.x, wave = t >> 6, lane = t & 63;
    const int row = blockIdx.x * 4 + wave;       // 0..10239
    const float2 v = *(const float2*)(cb + (size_t)row * 128 + lane * 2);
    ushort2 h, l;
    split16(v.x, h.x, l.x); split16(v.y, h.y, l.y);
    *(ushort2*)(cbh + (size_t)row * 128 + lane * 2) = h;
    *(ushort2*)(cbl + (size_t)row * 128 + lane * 2) = l;
    const float s = wave_sum(v.x * v.x + v.y * v.y);
    if (lane == 0) cnorm[row] = s;
}

// ---------------------------------------------------------------------------
// Expert histogram -> offsets (single block); zero the scatter counters.
// ---------------------------------------------------------------------------
__global__ __launch_bounds__(256)
void hist_kernel(const int* __restrict__ labels, int* __restrict__ off,
                 int* __restrict__ cnt) {
    __shared__ int h[10];
    const int t = threadIdx.x;
    if (t < 10) h[t] = 0;
    __syncthreads();
    for (int i = t; i < 32768; i += 256) atomicAdd(&h[labels[i]], 1);
    __syncthreads();
    if (t == 0) {
        int a = 0;
        for (int e = 0; e < 10; ++e) { off[e] = a; a += h[e]; }
        off[10] = a;
    }
    if (t < 10) cnt[t] = 0;
}

// Block-aggregated scatter: perm[pos] = row, rows grouped by expert.
__global__ __launch_bounds__(256)
void scatter_kernel(const int* __restrict__ labels, const int* __restrict__ off,
                    int* __restrict__ cnt, int* __restrict__ perm) {
    __shared__ int h[10], base[10];
    const int t = threadIdx.x;
    const int r = blockIdx.x * 256 + t;
    if (t < 10) h[t] = 0;
    __syncthreads();
    const int e = labels[r];
    const int lr = atomicAdd(&h[e], 1);
    __syncthreads();
    if (t < 10) base[t] = (h[t] > 0) ? atomicAdd(&cnt[t], h[t]) : 0;
    __syncthreads();
    perm[off[e] + base[e] + lr] = r;
}

// Gather z rows into permuted residual buffer (f32 + f16 hi/lo planes).
__global__ __launch_bounds__(256)
void gather_kernel(const int* __restrict__ perm, const float* __restrict__ z,
                   float* __restrict__ resp, uint16_t* __restrict__ resph,
                   uint16_t* __restrict__ respl) {
    const int t = threadIdx.x, wave = t >> 6, lane = t & 63;
    const int p = blockIdx.x * 4 + wave;
    const int r = perm[p];
    const float2 v = *(const float2*)(z + (size_t)r * 128 + lane * 2);
    *(float2*)(resp + (size_t)p * 128 + lane * 2) = v;
    ushort2 h, l;
    split16(v.x, h.x, l.x); split16(v.y, h.y, l.y);
    *(ushort2*)(resph + (size_t)p * 128 + lane * 2) = h;
    *(ushort2*)(respl + (size_t)p * 128 + lane * 2) = l;
}

// ---------------------------------------------------------------------------
// Fused RQ level: 64 rows (one expert) x 256 codewords per block.
// ---------------------------------------------------------------------------
#define BETA_F 0.001f

template<bool LAST>
__global__ __launch_bounds__(256)
void rq_level(int l, const int* __restrict__ off, const int* __restrict__ perm,
              const float* __restrict__ cb, const uint16_t* __restrict__ cbh,
              const uint16_t* __restrict__ cbl, const float* __restrict__ cnorm,
              float* __restrict__ resp, uint16_t* __restrict__ resph,
              uint16_t* __restrict__ respl, const float* __restrict__ z,
              float* __restrict__ out_idx, float* __restrict__ out_xq,
              float* __restrict__ out_loss, uint16_t* __restrict__ xqbf) {
    __shared__ __align__(16) uint16_t Ah[2048], Al[2048];   // 64 rows x 32 halves
    __shared__ __align__(16) uint16_t Bh[8192], Bl[8192];   // 256 cols x 32 halves
    __shared__ float redv[64][4];
    __shared__ int   redk[64][4];
    __shared__ int   kwin[64];
    __shared__ float wl[4];
    __shared__ int   soff[11];

    const int t = threadIdx.x, lane = t & 63, wave = t >> 6;
    if (t < 11) soff[t] = off[t];
    __syncthreads();

    int e = -1, tile = 0, acc = 0;
    #pragma unroll
    for (int i = 0; i < 10; ++i) {
        const int nb = (soff[i + 1] - soff[i] + 63) >> 6;
        if ((int)blockIdx.x < acc + nb && e < 0) { e = i; tile = blockIdx.x - acc; }
        acc += nb;
    }
    if (e < 0) return;
    const int p0 = soff[e] + tile * 64;
    const int nrows = min(64, soff[e + 1] - p0);
    const int le = l * 10 + e;

    const int l15 = lane & 15, quad = lane >> 4;
    const int wn = wave;

    const int ar = t >> 2;
    const int ac = (t & 3) ^ ((ar >> 1) & 3);
    const int arp = p0 + ((ar < nrows) ? ar : 0);
    const uint16_t* gAh = resph + (size_t)arp * 128 + ac * 8;
    const uint16_t* gAl = respl + (size_t)arp * 128 + ac * 8;
    const uint16_t* cbh_b = cbh + (size_t)le * 256 * 128;
    const uint16_t* cbl_b = cbl + (size_t)le * 256 * 128;

    f32x4 accM[4][4], accC[4][4];
    #pragma unroll
    for (int mi = 0; mi < 4; ++mi)
        #pragma unroll
        for (int nj = 0; nj < 4; ++nj)
            #pragma unroll
            for (int r = 0; r < 4; ++r) { accM[mi][nj][r] = 0.f; accC[mi][nj][r] = 0.f; }

    const int cpf = quad ^ ((l15 >> 1) & 3);

    for (int kc = 0; kc < 4; ++kc) {
        const int kk = kc * 32;
        __syncthreads();
        GLOAD_LDS16(gAh + kk, (char*)Ah + t * 16);
        GLOAD_LDS16(gAl + kk, (char*)Al + t * 16);
        #pragma unroll
        for (int rnd = 0; rnd < 4; ++rnd) {
            const int j = rnd * 256 + t;
            const int br = j >> 2;
            const int bc = (j & 3) ^ ((br >> 1) & 3);
            GLOAD_LDS16(cbh_b + (size_t)br * 128 + kk + bc * 8, (char*)Bh + j * 16);
            GLOAD_LDS16(cbl_b + (size_t)br * 128 + kk + bc * 8, (char*)Bl + j * 16);
        }
        __syncthreads();

        half8 ah[4], bh[4];
        #pragma unroll
        for (int i = 0; i < 4; ++i) {
            ah[i] = *(const half8*)((char*)Ah + ((i * 16 + l15) * 4 + cpf) * 16);
            bh[i] = *(const half8*)((char*)Bh + ((wn * 64 + i * 16 + l15) * 4 + cpf) * 16);
        }
        #pragma unroll
        for (int mi = 0; mi < 4; ++mi)
            #pragma unroll
            for (int nj = 0; nj < 4; ++nj)
                accM[mi][nj] = mfma16(ah[mi], bh[nj], accM[mi][nj]);

        half8 bl4[4];
        #pragma unroll
        for (int i = 0; i < 4; ++i)
            bl4[i] = *(const half8*)((char*)Bl + ((wn * 64 + i * 16 + l15) * 4 + cpf) * 16);
        #pragma unroll
        for (int mi = 0; mi < 4; ++mi)
            #pragma unroll
            for (int nj = 0; nj < 4; ++nj)
                accC[mi][nj] = mfma16(ah[mi], bl4[nj], accC[mi][nj]);

        half8 al4[4];
        #pragma unroll
        for (int i = 0; i < 4; ++i)
            al4[i] = *(const half8*)((char*)Al + ((i * 16 + l15) * 4 + cpf) * 16);
        #pragma unroll
        for (int mi = 0; mi < 4; ++mi)
            #pragma unroll
            for (int nj = 0; nj < 4; ++nj)
                accC[mi][nj] = mfma16(al4[mi], bh[nj], accC[mi][nj]);
    }

    // ---- scores + per-row argmin ----
    float cnv[4];
    #pragma unroll
    for (int nj = 0; nj < 4; ++nj)
        cnv[nj] = cnorm[le * 256 + wn * 64 + nj * 16 + l15];

    #pragma unroll
    for (int mi = 0; mi < 4; ++mi)
        #pragma unroll
        for (int r = 0; r < 4; ++r) {
            float bv = 1e30f; int bk = 0;
            #pragma unroll
            for (int nj = 0; nj < 4; ++nj) {
                const float d = cnv[nj] -
                    2.f * (accM[mi][nj][r] + accC[mi][nj][r] * (1.0f / 2048.0f));
                const int k = wn * 64 + nj * 16 + l15;
                if (d < bv || (d == bv && k < bk)) { bv = d; bk = k; }
            }
            #pragma unroll
            for (int o = 1; o < 16; o <<= 1) {
                const float ov = __shfl_xor(bv, o, 64);
                const int   ok = __shfl_xor(bk, o, 64);
                if (ov < bv || (ov == bv && ok < bk)) { bv = ov; bk = ok; }
            }
            const int row = mi * 16 + quad * 4 + r;
            if (l15 == 0) { redv[row][wn] = bv; redk[row][wn] = bk; }
        }
    __syncthreads();

    if (wave == 0) {
        const int row = lane;
        if (row < nrows) {
            float bv = redv[row][0]; int bk = redk[row][0];
            #pragma unroll
            for (int w = 1; w < 4; ++w) {
                const float ov = redv[row][w]; const int ok = redk[row][w];
                if (ov < bv || (ov == bv && ok < bk)) { bv = ov; bk = ok; }
            }
            kwin[row] = bk;
            out_idx[(size_t)perm[p0 + row] * 4 + l] = (float)bk;
        }
    }
    __syncthreads();

    // ---- exact fp32 residual update, loss, (LAST: x_q outputs) ----
    float lossw = 0.f;
    for (int i = 0; i < 16; ++i) {
        const int row = wave * 16 + i;
        if (row < nrows) {
            const int p = p0 + row;
            const int k = kwin[row];
            const float2 q2 = *(const float2*)(cb + ((size_t)le * 256 + k) * 128 + lane * 2);
            float2 r2 = *(float2*)(resp + (size_t)p * 128 + lane * 2);
            const float n0 = r2.x - q2.x, n1 = r2.y - q2.y;
            *(float2*)(resp + (size_t)p * 128 + lane * 2) = make_float2(n0, n1);
            if (!LAST) {
                ushort2 h, lo;
                split16(n0, h.x, lo.x); split16(n1, h.y, lo.y);
                *(ushort2*)(resph + (size_t)p * 128 + lane * 2) = h;
                *(ushort2*)(respl + (size_t)p * 128 + lane * 2) = lo;
            }
            lossw += wave_sum(n0 * n0 + n1 * n1);
            if (LAST) {
                const int orig = perm[p];
                const float2 z2 = *(const float2*)(z + (size_t)orig * 128 + lane * 2);
                const float xq0 = z2.x - n0, xq1 = z2.y - n1;
                out_xq[(size_t)orig * 128 + lane * 2]     = xq0;
                out_xq[(size_t)orig * 128 + lane * 2 + 1] = xq1;
                ushort2 xb; xb.x = f32_to_bf16(xq0); xb.y = f32_to_bf16(xq1);
                *(ushort2*)(xqbf + (size_t)orig * 128 + lane * 2) = xb;
            }
        }
    }
    if (lane == 0) wl[wave] = lossw;
    __syncthreads();
    if (t == 0)
        atomicAdd(out_loss, (wl[0] + wl[1] + wl[2] + wl[3]) *
                            ((1.0f + BETA_F) / (32768.0f * 128.0f)));
}

// ---------------------------------------------------------------------------

extern "C" void kernel_launch(void* const* d_in, const int* in_sizes, int n_in,
                              void* d_out, int out_size, void* d_ws, size_t ws_size,
                              hipStream_t stream) {
    const float* x      = (const float*)d_in[0];
    const int*   labels = (const int*)d_in[1];
    const float* ew[4]  = {(const float*)d_in[2], (const float*)d_in[4],
                           (const float*)d_in[6], (const float*)d_in[8]};
    const float* eb[4]  = {(const float*)d_in[3], (const float*)d_in[5],
                           (const float*)d_in[7], (const float*)d_in[9]};
    const float* dw[4]  = {(const float*)d_in[10], (const float*)d_in[12],
                           (const float*)d_in[14], (const float*)d_in[16]};
    const float* db[4]  = {(const float*)d_in[11], (const float*)d_in[13],
                           (const float*)d_in[15], (const float*)d_in[17]};
    const float* cb     = (const float*)d_in[18];

    float* out = (float*)d_out;
    const size_t LOSS_OFF = 25165824;
    const size_t IDX_OFF  = 25165825;
    const size_t XQ_OFF   = 25296897;

    // ---- workspace ----
    char* W = (char*)d_ws;
    size_t off_b = 0;
    auto alloc = [&](size_t bytes) { char* p = W + off_b; off_b += (bytes + 255) & ~(size_t)255; return p; };
    char*     region1 = alloc(134217728);          // 128 MiB (enc h1/h3, RQ bufs, dec d0/d2)
    char*     region2 = alloc(67108864);           // 64 MiB  (enc x/h2, dec d1)
    float*    z       = (float*)alloc(32768ull * 128 * 4);
    uint16_t* xqbf    = (uint16_t*)alloc(32768ull * 128 * 2);
    uint16_t* wtE0 = (uint16_t*)alloc(2ull *  768 * 2048 * 2);
    uint16_t* wtE1 = (uint16_t*)alloc(2ull * 2048 * 1024 * 2);
    uint16_t* wtE2 = (uint16_t*)alloc(2ull * 1024 *  512 * 2);
    uint16_t* wtE3 = (uint16_t*)alloc(2ull *  512 *  128 * 2);
    uint16_t* wtD0 = (uint16_t*)alloc(128ull  *  512 * 2);
    uint16_t* wtD1 = (uint16_t*)alloc(512ull  * 1024 * 2);
    uint16_t* wtD2 = (uint16_t*)alloc(1024ull * 2048 * 2);
    uint16_t* wtD3 = (uint16_t*)alloc(2048ull *  768 * 2);

    // RQ-phase buffers live inside region1 (free between encoder and decoder)
    char* r1 = region1;
    float*    resp  = (float*)r1;                      r1 += 32768ull * 128 * 4;
    uint16_t* resph = (uint16_t*)r1;                   r1 += 32768ull * 128 * 2;
    uint16_t* respl = (uint16_t*)r1;                   r1 += 32768ull * 128 * 2;
    uint16_t* cbh   = (uint16_t*)r1;                   r1 += 4ull * 10 * 256 * 128 * 2;
    uint16_t* cbl   = (uint16_t*)r1;                   r1 += 4ull * 10 * 256 * 128 * 2;
    float*    cnorm = (float*)r1;                      r1 += 4ull * 10 * 256 * 4;
    int*      permv = (int*)r1;                        r1 += 32768ull * 4;
    int*      eoff  = (int*)r1;                        r1 += 16 * 4;
    int*      ecnt  = (int*)r1;                        r1 += 16 * 4;

    dim3 blk(256);
    dim3 blk512(512);

    // ---- weight prep ----
    prep_w<0><<<dim3(2048/32,  768/32), blk, 0, stream>>>(ew[0], wtE0,  768, 2048);
    prep_w<0><<<dim3(1024/32, 2048/32), blk, 0, stream>>>(ew[1], wtE1, 2048, 1024);
    prep_w<0><<<dim3( 512/32, 1024/32), blk, 0, stream>>>(ew[2], wtE2, 1024,  512);
    prep_w<0><<<dim3( 128/32,  512/32), blk, 0, stream>>>(ew[3], wtE3,  512,  128);
    prep_w<1><<<dim3( 512/32,  128/32), blk, 0, stream>>>(dw[0], wtD0,  128,  512);
    prep_w<1><<<dim3(1024/32,  512/32), blk, 0, stream>>>(dw[1], wtD1,  512, 1024);
    prep_w<1><<<dim3(2048/32, 1024/32), blk, 0, stream>>>(dw[2], wtD2, 1024, 2048);
    prep_w<1><<<dim3( 768/32, 2048/32), blk, 0, stream>>>(dw[3], wtD3, 2048,  768);

    // ---- encoder in two M-halves: big layers on 128x256 reg-dbuf ----
    const int MH = 16384;
    for (int half = 0; half < 2; ++half) {
        const float* xh = x + (size_t)half * MH * 768;
        uint16_t* xpl = (uint16_t*)region2;
        split_x<<<1024, blk, 0, stream>>>(xh, xpl, xpl + (size_t)MH * 768, MH * 768 / 4);

        uint16_t* h1 = (uint16_t*)region1;
        gemm_256<true, true, true, 1><<<dim3(8, 128), blk512, 0, stream>>>(
            xpl, wtE0, eb[0], nullptr, h1, h1 + (size_t)MH * 2048, MH, 768, 2048);

        uint16_t* h2 = (uint16_t*)region2;
        gemm_256<true, true, true, 1><<<dim3(4, 128), blk512, 0, stream>>>(
            h1, wtE1, eb[1], nullptr, h2, h2 + (size_t)MH * 1024, MH, 2048, 1024);

        uint16_t* h3 = (uint16_t*)region1;
        gemm_256<true, true, true, 1><<<dim3(2, 128), blk512, 0, stream>>>(
            h2, wtE2, eb[2], nullptr, h3, h3 + (size_t)MH * 512, MH, 1024, 512);

        gemm_mfma<2, 2, 64, true, true, false, 0><<<dim3(2, 128), blk, 0, stream>>>(
            h3, wtE3, eb[3], z + (size_t)half * MH * 128, nullptr, nullptr, MH, 512, 128);
    }

    // ---- RQ prep (region1 now free) ----
    prep_cb2<<<2560, blk, 0, stream>>>(cb, cbh, cbl, cnorm);
    hist_kernel<<<1, blk, 0, stream>>>(labels, eoff, ecnt);
    scatter_kernel<<<128, blk, 0, stream>>>(labels, eoff, ecnt, permv);
    gather_kernel<<<8192, blk, 0, stream>>>(permv, z, resp, resph, respl);
    hipMemsetAsync((char*)d_out + LOSS_OFF * 4, 0, 4, stream);

    // ---- 4 RQ levels ----
    rq_level<false><<<522, blk, 0, stream>>>(0, eoff, permv, cb, cbh, cbl, cnorm,
        resp, resph, respl, z, out + IDX_OFF, out + XQ_OFF, out + LOSS_OFF, xqbf);
    rq_level<false><<<522, blk, 0, stream>>>(1, eoff, permv, cb, cbh, cbl, cnorm,
        resp, resph, respl, z, out + IDX_OFF, out + XQ_OFF, out + LOSS_OFF, xqbf);
    rq_level<false><<<522, blk, 0, stream>>>(2, eoff, permv, cb, cbh, cbl, cnorm,
        resp, resph, respl, z, out + IDX_OFF, out + XQ_OFF, out + LOSS_OFF, xqbf);
    rq_level<true ><<<522, blk, 0, stream>>>(3, eoff, permv, cb, cbh, cbl, cnorm,
        resp, resph, respl, z, out + IDX_OFF, out + XQ_OFF, out + LOSS_OFF, xqbf);

    // ---- decoder, bf16: d1..d3 on 128x256 reg-dbuf schedule ----
    const int M = 32768;
    uint16_t* d0 = (uint16_t*)region1;
    uint16_t* d1 = (uint16_t*)region2;
    uint16_t* d2 = (uint16_t*)region1;
    gemm_mfma<1, 3, 128, false, false, true, 2><<<dim3(4, 256), blk, 0, stream>>>(
        xqbf, wtD0, db[0], nullptr, d0, nullptr, M, 128, 512);
    gemm_256<false, false, true, 2><<<dim3(4, 256), blk512, 0, stream>>>(
        d0, wtD1, db[1], nullptr, d1, nullptr, M, 512, 1024);
    gemm_256<false, false, true, 2><<<dim3(8, 256), blk512, 0, stream>>>(
        d1, wtD2, db[2], nullptr, d2, nullptr, M, 1024, 2048);
    gemm_256<false, false, false, 0><<<dim3(3, 256), blk512, 0, stream>>>(
        d2, wtD3, db[3], out, nullptr, nullptr, M, 2048, 768);
}

// Round 7
// 1796.901 us; speedup vs baseline: 1.0541x; 1.0541x over previous
//
#include <hip/hip_runtime.h>
#include <cstdint>
#include <cstddef>

// ---------------------------------------------------------------------------
// MoE RQ-VAE forward.
//   Encoder: f16 split MFMA, FULL 3-product (hi*hi + hi*lo + lo*hi) on ALL
//            layers. ROUND-6 LESSON: dropping a1*b0 (~2^-11 on z) flips RQ
//            argmin picks -> integer index errors (absmax 225). z precision
//            is pinned by the argmin, not the float tolerance.
//   GEMM schedule: single-region K-step, NBUF=3, counted vmcnt, one barrier
//            per K-step (LDS reads only after vm->barrier certification).
//   Decoder: plain bf16, launch_bounds(512,4) -> VGPR<=128, 72KB LDS ->
//            2 blocks/CU (4 waves/SIMD) — the TLP the encoder can't have.
//   RQ: unchanged (full 3-product scores, exact fp32 residual update).
// ---------------------------------------------------------------------------

typedef _Float16 half8  __attribute__((ext_vector_type(8)));
typedef short    short8 __attribute__((ext_vector_type(8)));
typedef float    f32x4  __attribute__((ext_vector_type(4)));

__device__ __forceinline__ uint16_t f32_to_bf16(float v) {
    uint32_t u = __float_as_uint(v);
    u += 0x7fff + ((u >> 16) & 1);
    return (uint16_t)(u >> 16);
}
__device__ __forceinline__ uint16_t f32_to_f16_bits(float v) {
    _Float16 h = (_Float16)v;
    return __builtin_bit_cast(uint16_t, h);
}
__device__ __forceinline__ void split16(float v, uint16_t& hb, uint16_t& lb) {
    hb = f32_to_f16_bits(v);
    float hf = (float)__builtin_bit_cast(_Float16, hb);
    lb = f32_to_f16_bits((v - hf) * 2048.0f);
}

__device__ __forceinline__ float wave_sum(float v) {
    #pragma unroll
    for (int off = 32; off > 0; off >>= 1)
        v += __shfl_xor(v, off, 64);
    return v;
}

#define GLOAD_LDS16(g, l)                                                      \
    __builtin_amdgcn_global_load_lds(                                          \
        (const __attribute__((address_space(1))) void*)(g),                    \
        (__attribute__((address_space(3))) void*)(l), 16, 0, 0)

// counted waitcnt helpers
__device__ __forceinline__ void wait_vm(int nf) {
    if (nf >= 12)     asm volatile("s_waitcnt vmcnt(12)" ::: "memory");
    else if (nf >= 8) asm volatile("s_waitcnt vmcnt(8)"  ::: "memory");
    else if (nf >= 6) asm volatile("s_waitcnt vmcnt(6)"  ::: "memory");
    else if (nf >= 4) asm volatile("s_waitcnt vmcnt(4)"  ::: "memory");
    else              asm volatile("s_waitcnt vmcnt(0)"  ::: "memory");
}
template<int N>
__device__ __forceinline__ void wait_vmK() {
    if constexpr (N == 3)      asm volatile("s_waitcnt vmcnt(3)" ::: "memory");
    else if constexpr (N == 6) asm volatile("s_waitcnt vmcnt(6)" ::: "memory");
    else                       asm volatile("s_waitcnt vmcnt(0)" ::: "memory");
}
__device__ __forceinline__ void wait_lg0() { asm volatile("s_waitcnt lgkmcnt(0)" ::: "memory"); }

template<bool F16> struct VecT        { using type = half8;  };
template<>         struct VecT<false> { using type = short8; };

__device__ __forceinline__ f32x4 mfma16(half8 a, half8 b, f32x4 c) {
    return __builtin_amdgcn_mfma_f32_16x16x32_f16(a, b, c, 0, 0, 0);
}
__device__ __forceinline__ f32x4 mfma16(short8 a, short8 b, f32x4 c) {
    return __builtin_amdgcn_mfma_f32_16x16x32_bf16(a, b, c, 0, 0, 0);
}

// ---------------------------------------------------------------------------
// Wide-tile GEMM: C[M,N] = act(A[M,K] @ W[K,N] + bias)
// BM=128, BN=256, 512 threads (8 waves, 2M x 4N), wave tile 64x64.
// P = 3: full f16-split (encoder). P = 1: plain bf16 (decoder).
// NBUF=3, single region per K-step, one barrier, counted vmcnt(LPS) at the
// seam (tile it+1 certified collectively by vmcnt -> s_barrier).
// ---------------------------------------------------------------------------
template<int P, bool ISF16, bool RELU, int OUT>
__global__ __launch_bounds__(512, (P >= 2) ? 2 : 4)
void gemm_256(const uint16_t* __restrict__ A, const uint16_t* __restrict__ Wt,
              const float* __restrict__ bias,
              float* __restrict__ Cf, uint16_t* __restrict__ C0,
              uint16_t* __restrict__ C1, int M, int K, int N) {
    using vec8 = typename VecT<ISF16>::type;
    constexpr int ABYT   = 8192;                  // 128 rows x 32k x 2B per plane
    constexpr int BBYT   = 16384;                 // 256 rows x 32k x 2B per plane
    constexpr int ATOT   = (P == 3) ? 2 * ABYT : ABYT;
    constexpr int TILE_B = ATOT + ((P >= 2) ? 2 : 1) * BBYT;  // 49152 | 24576
    constexpr int NBUF   = 3;
    constexpr int LPS    = (P == 3) ? 6 : 3;      // gloads per thread per K-step
    __shared__ __align__(16) char lds[NBUF * TILE_B];

    const int t    = threadIdx.x;
    const int lane = t & 63, wave = t >> 6;       // 8 waves
    const int wm = wave >> 2, wn = wave & 3;
    const int bm = blockIdx.y, bn = blockIdx.x;

    const size_t planeA = (size_t)M * K;
    const size_t planeB = (size_t)N * K;

    // staging source: thread t covers row r, xor-swizzled 16B chunk c
    const int r = t >> 2;
    const int c = (t & 3) ^ ((r >> 1) & 3);
    const uint16_t* gA  = A  + (size_t)(bm * 128 + r) * K + c * 8;
    const uint16_t* gB0 = Wt + (size_t)(bn * 256 + r) * K + c * 8;
    const uint16_t* gB1 = Wt + (size_t)(bn * 256 + 128 + r) * K + c * 8;

    const int l15 = lane & 15, quad = lane >> 4;
    const int cpf = quad ^ ((l15 >> 1) & 3);
    const int aoff = ((wm * 64 + l15) * 4 + cpf) * 16;
    const int boff = ((wn * 64 + l15) * 4 + cpf) * 16;

    f32x4 accM[4][4], accC[4][4];
    #pragma unroll
    for (int mi = 0; mi < 4; ++mi)
        #pragma unroll
        for (int nj = 0; nj < 4; ++nj)
            #pragma unroll
            for (int rr = 0; rr < 4; ++rr) { accM[mi][nj][rr] = 0.f; if (P >= 2) accC[mi][nj][rr] = 0.f; }

    const int nt = K >> 5;                        // >= 2 for all layer shapes

    auto stage = [&](int ti, int bi) {
        char* b = (char*)lds + bi * TILE_B;
        const int kb = ti * 32;
        GLOAD_LDS16(gA + kb, b + t * 16);                             // A hi
        if (P == 3) GLOAD_LDS16(gA + planeA + kb, b + ABYT + t * 16); // A lo
        GLOAD_LDS16(gB0 + kb, b + ATOT + t * 16);                     // B hi
        GLOAD_LDS16(gB1 + kb, b + ATOT + 8192 + t * 16);
        if (P >= 2) {
            GLOAD_LDS16(gB0 + planeB + kb, b + ATOT + BBYT + t * 16); // B lo
            GLOAD_LDS16(gB1 + planeB + kb, b + ATOT + BBYT + 8192 + t * 16);
        }
    };

    // prologue: tiles 0 and 1 in flight
    stage(0, 0);
    stage(1, 1);
    wait_vmK<LPS>();                              // tile 0 resident
    __builtin_amdgcn_sched_barrier(0);
    __builtin_amdgcn_s_barrier();

    int cur = 0;
    for (int it = 0; it < nt; ++it) {
        char* bufc = (char*)lds + cur * TILE_B;
        const int nx = it + 2;
        int bi = cur + 2; if (bi >= NBUF) bi -= NBUF;

        // issue next-next tile's staging first (latency hides under region)
        if (nx < nt) stage(nx, bi);

        vec8 a0[4], b0[4];
        #pragma unroll
        for (int i = 0; i < 4; ++i) {
            a0[i] = *(const vec8*)(bufc + aoff + i * 1024);
            b0[i] = *(const vec8*)(bufc + ATOT + boff + i * 1024);
        }
        #pragma unroll
        for (int mi = 0; mi < 4; ++mi)
            #pragma unroll
            for (int nj = 0; nj < 4; ++nj)
                accM[mi][nj] = mfma16(a0[mi], b0[nj], accM[mi][nj]);

        if constexpr (P >= 2) {
            vec8 b1[4];
            #pragma unroll
            for (int i = 0; i < 4; ++i)
                b1[i] = *(const vec8*)(bufc + ATOT + BBYT + boff + i * 1024);
            #pragma unroll
            for (int mi = 0; mi < 4; ++mi)
                #pragma unroll
                for (int nj = 0; nj < 4; ++nj)
                    accC[mi][nj] = mfma16(a0[mi], b1[nj], accC[mi][nj]);
        }
        if constexpr (P == 3) {
            vec8 a1[4];
            #pragma unroll
            for (int i = 0; i < 4; ++i)
                a1[i] = *(const vec8*)(bufc + ABYT + aoff + i * 1024);
            #pragma unroll
            for (int mi = 0; mi < 4; ++mi)
                #pragma unroll
                for (int nj = 0; nj < 4; ++nj)
                    accC[mi][nj] = mfma16(a1[mi], b0[nj], accC[mi][nj]);
        }

        // seam: my LDS reads done; tile it+1 resident; one barrier
        wait_lg0();
        wait_vmK<LPS>();
        __builtin_amdgcn_sched_barrier(0);
        __builtin_amdgcn_s_barrier();
        __builtin_amdgcn_sched_barrier(0);

        cur = cur + 1; if (cur == NBUF) cur = 0;
    }

    if (P >= 2) {
        #pragma unroll
        for (int mi = 0; mi < 4; ++mi)
            #pragma unroll
            for (int nj = 0; nj < 4; ++nj)
                #pragma unroll
                for (int rr = 0; rr < 4; ++rr)
                    accM[mi][nj][rr] += accC[mi][nj][rr] * (1.0f / 2048.0f);
    }

    const int colb = bn * 256 + wn * 64 + l15;
    const int rowb = bm * 128 + wm * 64 + quad * 4;
    float bz[4];
    #pragma unroll
    for (int nj = 0; nj < 4; ++nj) bz[nj] = bias[colb + nj * 16];

    #pragma unroll
    for (int mi = 0; mi < 4; ++mi)
        #pragma unroll
        for (int nj = 0; nj < 4; ++nj)
            #pragma unroll
            for (int rr = 0; rr < 4; ++rr) {
                float v = accM[mi][nj][rr] + bz[nj];
                if (RELU) v = fmaxf(v, 0.f);
                const size_t o = (size_t)(rowb + mi * 16 + rr) * N + colb + nj * 16;
                if (OUT == 0) {
                    Cf[o] = v;
                } else if (OUT == 1) {
                    uint16_t hb, lb; split16(v, hb, lb);
                    C0[o] = hb; C1[o] = lb;
                } else {
                    C0[o] = f32_to_bf16(v);
                }
            }
}

// ---------------------------------------------------------------------------
// 128-row 4-wave pipelined GEMM for tiny layers (full 3-product CORR).
// ---------------------------------------------------------------------------
template<int NPL, int NBUF, int BN, bool ISF16, bool CORR, bool RELU, int OUT>
__global__ __launch_bounds__(256)
void gemm_mfma(const uint16_t* __restrict__ A, const uint16_t* __restrict__ Wt,
               const float* __restrict__ bias,
               float* __restrict__ Cf, uint16_t* __restrict__ C0,
               uint16_t* __restrict__ C1, int M, int K, int N) {
    using vec8 = typename VecT<ISF16>::type;
    constexpr int APL    = 8192;
    constexpr int BPL    = BN * 64;
    constexpr int TILE_B = NPL * (APL + BPL);
    constexpr int BSHOT  = BN / 64;
    constexpr int NR     = BN / 32;
    constexpr int LPT    = NPL * (2 + BSHOT);
    __shared__ __align__(16) char lds[NBUF * TILE_B];

    const int t    = threadIdx.x;
    const int lane = t & 63, wave = t >> 6;
    const int wm = wave >> 1, wn = wave & 1;
    const int bm = blockIdx.y, bn = blockIdx.x;

    const size_t planeA = (size_t)M * K;
    const size_t planeB = (size_t)N * K;

    const int r0 = t >> 2,        c0 = (t & 3) ^ ((r0 >> 1) & 3);
    const int r1 = 64 + (t >> 2), c1 = (t & 3) ^ ((r1 >> 1) & 3);

    const uint16_t* gA0 = A + (size_t)(bm * 128 + r0) * K + c0 * 8;
    const uint16_t* gA1 = A + (size_t)(bm * 128 + r1) * K + c1 * 8;
    const uint16_t* gB[2];
    gB[0] = Wt + (size_t)(bn * BN + r0) * K + c0 * 8;
    if (BSHOT == 2) gB[1] = Wt + (size_t)(bn * BN + r1) * K + c1 * 8;

    const int wb = wave * 1024;
    const int l15 = lane & 15, quad = lane >> 4;
    const int cpf = quad ^ ((l15 >> 1) & 3);
    const int aoff = ((wm * 64 + l15) * 4 + cpf) * 16;
    const int boff = ((wn * (BN / 2) + l15) * 4 + cpf) * 16;

    f32x4 accM[4][NR], accC[4][NR];
    #pragma unroll
    for (int mi = 0; mi < 4; ++mi)
        #pragma unroll
        for (int nj = 0; nj < NR; ++nj)
            #pragma unroll
            for (int r = 0; r < 4; ++r) { accM[mi][nj][r] = 0.f; if (CORR) accC[mi][nj][r] = 0.f; }

    const int nt = K >> 5;

    auto stage = [&](int ti, int bi) {
        char* bA = (char*)lds + bi * TILE_B;
        char* bB = bA + NPL * APL;
        const int kb = ti * 32;
        #pragma unroll
        for (int p = 0; p < NPL; ++p) {
            GLOAD_LDS16(gA0 + (size_t)p * planeA + kb, bA + p * APL + wb);
            GLOAD_LDS16(gA1 + (size_t)p * planeA + kb, bA + p * APL + 4096 + wb);
            #pragma unroll
            for (int s = 0; s < BSHOT; ++s)
                GLOAD_LDS16(gB[s] + (size_t)p * planeB + kb, bB + p * BPL + s * 4096 + wb);
        }
    };

    #pragma unroll
    for (int i = 0; i < NBUF - 1; ++i) stage(i, i);

    int cur = 0;
    for (int it = 0; it < nt; ++it) {
        const int nx = it + NBUF - 1;
        if (nx < nt) {
            int bi = cur + NBUF - 1; if (bi >= NBUF) bi -= NBUF;
            stage(nx, bi);
        }
        const int rem = nt - 1 - it;
        const int nf  = (rem < NBUF - 1 ? rem : NBUF - 1) * LPT;
        wait_vm(nf);
        __builtin_amdgcn_sched_barrier(0);
        __builtin_amdgcn_s_barrier();
        __builtin_amdgcn_sched_barrier(0);

        char* bA = (char*)lds + cur * TILE_B;
        char* bB = bA + NPL * APL;

        vec8 a0[4], b0[NR];
        #pragma unroll
        for (int i = 0; i < 4; ++i)
            a0[i] = *(const vec8*)(bA + aoff + i * 1024);
        #pragma unroll
        for (int i = 0; i < NR; ++i)
            b0[i] = *(const vec8*)(bB + boff + i * 1024);
        #pragma unroll
        for (int mi = 0; mi < 4; ++mi)
            #pragma unroll
            for (int nj = 0; nj < NR; ++nj)
                accM[mi][nj] = mfma16(a0[mi], b0[nj], accM[mi][nj]);

        if (CORR) {
            vec8 b1[NR];
            #pragma unroll
            for (int i = 0; i < NR; ++i)
                b1[i] = *(const vec8*)(bB + BPL + boff + i * 1024);
            #pragma unroll
            for (int mi = 0; mi < 4; ++mi)
                #pragma unroll
                for (int nj = 0; nj < NR; ++nj)
                    accC[mi][nj] = mfma16(a0[mi], b1[nj], accC[mi][nj]);
            vec8 a1[4];
            #pragma unroll
            for (int i = 0; i < 4; ++i)
                a1[i] = *(const vec8*)(bA + APL + aoff + i * 1024);
            #pragma unroll
            for (int mi = 0; mi < 4; ++mi)
                #pragma unroll
                for (int nj = 0; nj < NR; ++nj)
                    accC[mi][nj] = mfma16(a1[mi], b0[nj], accC[mi][nj]);
        }

        wait_lg0();
        __builtin_amdgcn_sched_barrier(0);
        __builtin_amdgcn_s_barrier();
        __builtin_amdgcn_sched_barrier(0);

        cur = cur + 1; if (cur == NBUF) cur = 0;
    }

    if (CORR) {
        #pragma unroll
        for (int mi = 0; mi < 4; ++mi)
            #pragma unroll
            for (int nj = 0; nj < NR; ++nj)
                #pragma unroll
                for (int r = 0; r < 4; ++r)
                    accM[mi][nj][r] += accC[mi][nj][r] * (1.0f / 2048.0f);
    }

    const int colb = bn * BN + wn * (BN / 2) + l15;
    const int rowb = bm * 128 + wm * 64 + quad * 4;
    float bz[NR];
    #pragma unroll
    for (int nj = 0; nj < NR; ++nj) bz[nj] = bias[colb + nj * 16];

    #pragma unroll
    for (int mi = 0; mi < 4; ++mi)
        #pragma unroll
        for (int nj = 0; nj < NR; ++nj)
            #pragma unroll
            for (int r = 0; r < 4; ++r) {
                float v = accM[mi][nj][r] + bz[nj];
                if (RELU) v = fmaxf(v, 0.f);
                const size_t o = (size_t)(rowb + mi * 16 + r) * N + colb + nj * 16;
                if (OUT == 0) {
                    Cf[o] = v;
                } else if (OUT == 1) {
                    uint16_t hb, lb; split16(v, hb, lb);
                    C0[o] = hb; C1[o] = lb;
                } else {
                    C0[o] = f32_to_bf16(v);
                }
            }
}

// ---------------------------------------------------------------------------
// Weight prep (unchanged)
// ---------------------------------------------------------------------------
template<int MODE>
__global__ __launch_bounds__(256)
void prep_w(const float* __restrict__ W, uint16_t* __restrict__ out, int K, int N) {
    __shared__ float tile[32][33];
    const int tx = threadIdx.x & 31, ty = threadIdx.x >> 5;
    const int n0 = blockIdx.x * 32, k0 = blockIdx.y * 32;
    #pragma unroll
    for (int i = 0; i < 4; ++i)
        tile[ty + i * 8][tx] = W[(size_t)(k0 + ty + i * 8) * N + n0 + tx];
    __syncthreads();
    #pragma unroll
    for (int i = 0; i < 4; ++i) {
        float v = tile[tx][ty + i * 8];
        size_t o = (size_t)(n0 + ty + i * 8) * K + k0 + tx;
        if (MODE == 0) {
            uint16_t hb, lb; split16(v, hb, lb);
            out[o] = hb;
            out[o + (size_t)N * K] = lb;
        } else {
            out[o] = f32_to_bf16(v);
        }
    }
}

__global__ __launch_bounds__(256)
void split_x(const float* __restrict__ x, uint16_t* __restrict__ hi,
             uint16_t* __restrict__ lo, int n4) {
    int i = blockIdx.x * 256 + threadIdx.x;
    const int stride = gridDim.x * 256;
    for (; i < n4; i += stride) {
        float4 v = ((const float4*)x)[i];
        ushort4 h, l;
        split16(v.x, h.x, l.x); split16(v.y, h.y, l.y);
        split16(v.z, h.z, l.z); split16(v.w, h.w, l.w);
        ((ushort4*)hi)[i] = h;
        ((ushort4*)lo)[i] = l;
    }
}

// ---------------------------------------------------------------------------
// Codebook prep: f16 hi/lo planes [l][e][k][d] + cnorm. One wave per row.
// ---------------------------------------------------------------------------
__global__ __launch_bounds__(256)
void prep_cb2(const float* __restrict__ cb, uint16_t* __restrict__ cbh,
              uint16_t* __restrict__ cbl, float* __restrict__ cnorm) {
    const int t = threadIdx.x, wave = t >> 6, lane = t & 63;
    const int row = blockIdx.x * 4 + wave;       // 0..10239
    const float2 v = *(const float2*)(cb + (size_t)row * 128 + lane * 2);
    ushort2 h, l;
    split16(v.x, h.x, l.x); split16(v.y, h.y, l.y);
    *(ushort2*)(cbh + (size_t)row * 128 + lane * 2) = h;
    *(ushort2*)(cbl + (size_t)row * 128 + lane * 2) = l;
    const float s = wave_sum(v.x * v.x + v.y * v.y);
    if (lane == 0) cnorm[row] = s;
}

// ---------------------------------------------------------------------------
// Expert histogram -> offsets (single block); zero the scatter counters.
// ---------------------------------------------------------------------------
__global__ __launch_bounds__(256)
void hist_kernel(const int* __restrict__ labels, int* __restrict__ off,
                 int* __restrict__ cnt) {
    __shared__ int h[10];
    const int t = threadIdx.x;
    if (t < 10) h[t] = 0;
    __syncthreads();
    for (int i = t; i < 32768; i += 256) atomicAdd(&h[labels[i]], 1);
    __syncthreads();
    if (t == 0) {
        int a = 0;
        for (int e = 0; e < 10; ++e) { off[e] = a; a += h[e]; }
        off[10] = a;
    }
    if (t < 10) cnt[t] = 0;
}

// Block-aggregated scatter: perm[pos] = row, rows grouped by expert.
__global__ __launch_bounds__(256)
void scatter_kernel(const int* __restrict__ labels, const int* __restrict__ off,
                    int* __restrict__ cnt, int* __restrict__ perm) {
    __shared__ int h[10], base[10];
    const int t = threadIdx.x;
    const int r = blockIdx.x * 256 + t;
    if (t < 10) h[t] = 0;
    __syncthreads();
    const int e = labels[r];
    const int lr = atomicAdd(&h[e], 1);
    __syncthreads();
    if (t < 10) base[t] = (h[t] > 0) ? atomicAdd(&cnt[t], h[t]) : 0;
    __syncthreads();
    perm[off[e] + base[e] + lr] = r;
}

// Gather z rows into permuted residual buffer (f32 + f16 hi/lo planes).
__global__ __launch_bounds__(256)
void gather_kernel(const int* __restrict__ perm, const float* __restrict__ z,
                   float* __restrict__ resp, uint16_t* __restrict__ resph,
                   uint16_t* __restrict__ respl) {
    const int t = threadIdx.x, wave = t >> 6, lane = t & 63;
    const int p = blockIdx.x * 4 + wave;
    const int r = perm[p];
    const float2 v = *(const float2*)(z + (size_t)r * 128 + lane * 2);
    *(float2*)(resp + (size_t)p * 128 + lane * 2) = v;
    ushort2 h, l;
    split16(v.x, h.x, l.x); split16(v.y, h.y, l.y);
    *(ushort2*)(resph + (size_t)p * 128 + lane * 2) = h;
    *(ushort2*)(respl + (size_t)p * 128 + lane * 2) = l;
}

// ---------------------------------------------------------------------------
// Fused RQ level: 64 rows (one expert) x 256 codewords per block.
// ---------------------------------------------------------------------------
#define BETA_F 0.001f

template<bool LAST>
__global__ __launch_bounds__(256)
void rq_level(int l, const int* __restrict__ off, const int* __restrict__ perm,
              const float* __restrict__ cb, const uint16_t* __restrict__ cbh,
              const uint16_t* __restrict__ cbl, const float* __restrict__ cnorm,
              float* __restrict__ resp, uint16_t* __restrict__ resph,
              uint16_t* __restrict__ respl, const float* __restrict__ z,
              float* __restrict__ out_idx, float* __restrict__ out_xq,
              float* __restrict__ out_loss, uint16_t* __restrict__ xqbf) {
    __shared__ __align__(16) uint16_t Ah[2048], Al[2048];   // 64 rows x 32 halves
    __shared__ __align__(16) uint16_t Bh[8192], Bl[8192];   // 256 cols x 32 halves
    __shared__ float redv[64][4];
    __shared__ int   redk[64][4];
    __shared__ int   kwin[64];
    __shared__ float wl[4];
    __shared__ int   soff[11];

    const int t = threadIdx.x, lane = t & 63, wave = t >> 6;
    if (t < 11) soff[t] = off[t];
    __syncthreads();

    int e = -1, tile = 0, acc = 0;
    #pragma unroll
    for (int i = 0; i < 10; ++i) {
        const int nb = (soff[i + 1] - soff[i] + 63) >> 6;
        if ((int)blockIdx.x < acc + nb && e < 0) { e = i; tile = blockIdx.x - acc; }
        acc += nb;
    }
    if (e < 0) return;
    const int p0 = soff[e] + tile * 64;
    const int nrows = min(64, soff[e + 1] - p0);
    const int le = l * 10 + e;

    const int l15 = lane & 15, quad = lane >> 4;
    const int wn = wave;

    const int ar = t >> 2;
    const int ac = (t & 3) ^ ((ar >> 1) & 3);
    const int arp = p0 + ((ar < nrows) ? ar : 0);
    const uint16_t* gAh = resph + (size_t)arp * 128 + ac * 8;
    const uint16_t* gAl = respl + (size_t)arp * 128 + ac * 8;
    const uint16_t* cbh_b = cbh + (size_t)le * 256 * 128;
    const uint16_t* cbl_b = cbl + (size_t)le * 256 * 128;

    f32x4 accM[4][4], accC[4][4];
    #pragma unroll
    for (int mi = 0; mi < 4; ++mi)
        #pragma unroll
        for (int nj = 0; nj < 4; ++nj)
            #pragma unroll
            for (int r = 0; r < 4; ++r) { accM[mi][nj][r] = 0.f; accC[mi][nj][r] = 0.f; }

    const int cpf = quad ^ ((l15 >> 1) & 3);

    for (int kc = 0; kc < 4; ++kc) {
        const int kk = kc * 32;
        __syncthreads();
        GLOAD_LDS16(gAh + kk, (char*)Ah + t * 16);
        GLOAD_LDS16(gAl + kk, (char*)Al + t * 16);
        #pragma unroll
        for (int rnd = 0; rnd < 4; ++rnd) {
            const int j = rnd * 256 + t;
            const int br = j >> 2;
            const int bc = (j & 3) ^ ((br >> 1) & 3);
            GLOAD_LDS16(cbh_b + (size_t)br * 128 + kk + bc * 8, (char*)Bh + j * 16);
            GLOAD_LDS16(cbl_b + (size_t)br * 128 + kk + bc * 8, (char*)Bl + j * 16);
        }
        __syncthreads();

        half8 ah[4], bh[4];
        #pragma unroll
        for (int i = 0; i < 4; ++i) {
            ah[i] = *(const half8*)((char*)Ah + ((i * 16 + l15) * 4 + cpf) * 16);
            bh[i] = *(const half8*)((char*)Bh + ((wn * 64 + i * 16 + l15) * 4 + cpf) * 16);
        }
        #pragma unroll
        for (int mi = 0; mi < 4; ++mi)
            #pragma unroll
            for (int nj = 0; nj < 4; ++nj)
                accM[mi][nj] = mfma16(ah[mi], bh[nj], accM[mi][nj]);

        half8 bl4[4];
        #pragma unroll
        for (int i = 0; i < 4; ++i)
            bl4[i] = *(const half8*)((char*)Bl + ((wn * 64 + i * 16 + l15) * 4 + cpf) * 16);
        #pragma unroll
        for (int mi = 0; mi < 4; ++mi)
            #pragma unroll
            for (int nj = 0; nj < 4; ++nj)
                accC[mi][nj] = mfma16(ah[mi], bl4[nj], accC[mi][nj]);

        half8 al4[4];
        #pragma unroll
        for (int i = 0; i < 4; ++i)
            al4[i] = *(const half8*)((char*)Al + ((i * 16 + l15) * 4 + cpf) * 16);
        #pragma unroll
        for (int mi = 0; mi < 4; ++mi)
            #pragma unroll
            for (int nj = 0; nj < 4; ++nj)
                accC[mi][nj] = mfma16(al4[mi], bh[nj], accC[mi][nj]);
    }

    // ---- scores + per-row argmin ----
    float cnv[4];
    #pragma unroll
    for (int nj = 0; nj < 4; ++nj)
        cnv[nj] = cnorm[le * 256 + wn * 64 + nj * 16 + l15];

    #pragma unroll
    for (int mi = 0; mi < 4; ++mi)
        #pragma unroll
        for (int r = 0; r < 4; ++r) {
            float bv = 1e30f; int bk = 0;
            #pragma unroll
            for (int nj = 0; nj < 4; ++nj) {
                const float d = cnv[nj] -
                    2.f * (accM[mi][nj][r] + accC[mi][nj][r] * (1.0f / 2048.0f));
                const int k = wn * 64 + nj * 16 + l15;
                if (d < bv || (d == bv && k < bk)) { bv = d; bk = k; }
            }
            #pragma unroll
            for (int o = 1; o < 16; o <<= 1) {
                const float ov = __shfl_xor(bv, o, 64);
                const int   ok = __shfl_xor(bk, o, 64);
                if (ov < bv || (ov == bv && ok < bk)) { bv = ov; bk = ok; }
            }
            const int row = mi * 16 + quad * 4 + r;
            if (l15 == 0) { redv[row][wn] = bv; redk[row][wn] = bk; }
        }
    __syncthreads();

    if (wave == 0) {
        const int row = lane;
        if (row < nrows) {
            float bv = redv[row][0]; int bk = redk[row][0];
            #pragma unroll
            for (int w = 1; w < 4; ++w) {
                const float ov = redv[row][w]; const int ok = redk[row][w];
                if (ov < bv || (ov == bv && ok < bk)) { bv = ov; bk = ok; }
            }
            kwin[row] = bk;
            out_idx[(size_t)perm[p0 + row] * 4 + l] = (float)bk;
        }
    }
    __syncthreads();

    // ---- exact fp32 residual update, loss, (LAST: x_q outputs) ----
    float lossw = 0.f;
    for (int i = 0; i < 16; ++i) {
        const int row = wave * 16 + i;
        if (row < nrows) {
            const int p = p0 + row;
            const int k = kwin[row];
            const float2 q2 = *(const float2*)(cb + ((size_t)le * 256 + k) * 128 + lane * 2);
            float2 r2 = *(float2*)(resp + (size_t)p * 128 + lane * 2);
            const float n0 = r2.x - q2.x, n1 = r2.y - q2.y;
            *(float2*)(resp + (size_t)p * 128 + lane * 2) = make_float2(n0, n1);
            if (!LAST) {
                ushort2 h, lo;
                split16(n0, h.x, lo.x); split16(n1, h.y, lo.y);
                *(ushort2*)(resph + (size_t)p * 128 + lane * 2) = h;
                *(ushort2*)(respl + (size_t)p * 128 + lane * 2) = lo;
            }
            lossw += wave_sum(n0 * n0 + n1 * n1);
            if (LAST) {
                const int orig = perm[p];
                const float2 z2 = *(const float2*)(z + (size_t)orig * 128 + lane * 2);
                const float xq0 = z2.x - n0, xq1 = z2.y - n1;
                out_xq[(size_t)orig * 128 + lane * 2]     = xq0;
                out_xq[(size_t)orig * 128 + lane * 2 + 1] = xq1;
                ushort2 xb; xb.x = f32_to_bf16(xq0); xb.y = f32_to_bf16(xq1);
                *(ushort2*)(xqbf + (size_t)orig * 128 + lane * 2) = xb;
            }
        }
    }
    if (lane == 0) wl[wave] = lossw;
    __syncthreads();
    if (t == 0)
        atomicAdd(out_loss, (wl[0] + wl[1] + wl[2] + wl[3]) *
                            ((1.0f + BETA_F) / (32768.0f * 128.0f)));
}

// ---------------------------------------------------------------------------

extern "C" void kernel_launch(void* const* d_in, const int* in_sizes, int n_in,
                              void* d_out, int out_size, void* d_ws, size_t ws_size,
                              hipStream_t stream) {
    const float* x      = (const float*)d_in[0];
    const int*   labels = (const int*)d_in[1];
    const float* ew[4]  = {(const float*)d_in[2], (const float*)d_in[4],
                           (const float*)d_in[6], (const float*)d_in[8]};
    const float* eb[4]  = {(const float*)d_in[3], (const float*)d_in[5],
                           (const float*)d_in[7], (const float*)d_in[9]};
    const float* dw[4]  = {(const float*)d_in[10], (const float*)d_in[12],
                           (const float*)d_in[14], (const float*)d_in[16]};
    const float* db[4]  = {(const float*)d_in[11], (const float*)d_in[13],
                           (const float*)d_in[15], (const float*)d_in[17]};
    const float* cb     = (const float*)d_in[18];

    float* out = (float*)d_out;
    const size_t LOSS_OFF = 25165824;
    const size_t IDX_OFF  = 25165825;
    const size_t XQ_OFF   = 25296897;

    // ---- workspace ----
    char* W = (char*)d_ws;
    size_t off_b = 0;
    auto alloc = [&](size_t bytes) { char* p = W + off_b; off_b += (bytes + 255) & ~(size_t)255; return p; };
    char*     region1 = alloc(134217728);          // 128 MiB (enc h1/h3, RQ bufs, dec d0/d2)
    char*     region2 = alloc(67108864);           // 64 MiB  (enc x/h2, dec d1)
    float*    z       = (float*)alloc(32768ull * 128 * 4);
    uint16_t* xqbf    = (uint16_t*)alloc(32768ull * 128 * 2);
    uint16_t* wtE0 = (uint16_t*)alloc(2ull *  768 * 2048 * 2);
    uint16_t* wtE1 = (uint16_t*)alloc(2ull * 2048 * 1024 * 2);
    uint16_t* wtE2 = (uint16_t*)alloc(2ull * 1024 *  512 * 2);
    uint16_t* wtE3 = (uint16_t*)alloc(2ull *  512 *  128 * 2);
    uint16_t* wtD0 = (uint16_t*)alloc(128ull  *  512 * 2);
    uint16_t* wtD1 = (uint16_t*)alloc(512ull  * 1024 * 2);
    uint16_t* wtD2 = (uint16_t*)alloc(1024ull * 2048 * 2);
    uint16_t* wtD3 = (uint16_t*)alloc(2048ull *  768 * 2);

    // RQ-phase buffers live inside region1 (free between encoder and decoder)
    char* r1 = region1;
    float*    resp  = (float*)r1;                      r1 += 32768ull * 128 * 4;
    uint16_t* resph = (uint16_t*)r1;                   r1 += 32768ull * 128 * 2;
    uint16_t* respl = (uint16_t*)r1;                   r1 += 32768ull * 128 * 2;
    uint16_t* cbh   = (uint16_t*)r1;                   r1 += 4ull * 10 * 256 * 128 * 2;
    uint16_t* cbl   = (uint16_t*)r1;                   r1 += 4ull * 10 * 256 * 128 * 2;
    float*    cnorm = (float*)r1;                      r1 += 4ull * 10 * 256 * 4;
    int*      permv = (int*)r1;                        r1 += 32768ull * 4;
    int*      eoff  = (int*)r1;                        r1 += 16 * 4;
    int*      ecnt  = (int*)r1;                        r1 += 16 * 4;

    dim3 blk(256);
    dim3 blk512(512);

    // ---- weight prep ----
    prep_w<0><<<dim3(2048/32,  768/32), blk, 0, stream>>>(ew[0], wtE0,  768, 2048);
    prep_w<0><<<dim3(1024/32, 2048/32), blk, 0, stream>>>(ew[1], wtE1, 2048, 1024);
    prep_w<0><<<dim3( 512/32, 1024/32), blk, 0, stream>>>(ew[2], wtE2, 1024,  512);
    prep_w<0><<<dim3( 128/32,  512/32), blk, 0, stream>>>(ew[3], wtE3,  512,  128);
    prep_w<1><<<dim3( 512/32,  128/32), blk, 0, stream>>>(dw[0], wtD0,  128,  512);
    prep_w<1><<<dim3(1024/32,  512/32), blk, 0, stream>>>(dw[1], wtD1,  512, 1024);
    prep_w<1><<<dim3(2048/32, 1024/32), blk, 0, stream>>>(dw[2], wtD2, 1024, 2048);
    prep_w<1><<<dim3( 768/32, 2048/32), blk, 0, stream>>>(dw[3], wtD3, 2048,  768);

    // ---- encoder in two M-halves: full 3-product everywhere ----
    const int MH = 16384;
    for (int half = 0; half < 2; ++half) {
        const float* xh = x + (size_t)half * MH * 768;
        uint16_t* xpl = (uint16_t*)region2;
        split_x<<<1024, blk, 0, stream>>>(xh, xpl, xpl + (size_t)MH * 768, MH * 768 / 4);

        uint16_t* h1 = (uint16_t*)region1;
        gemm_256<3, true, true, 1><<<dim3(8, 128), blk512, 0, stream>>>(
            xpl, wtE0, eb[0], nullptr, h1, h1 + (size_t)MH * 2048, MH, 768, 2048);

        uint16_t* h2 = (uint16_t*)region2;
        gemm_256<3, true, true, 1><<<dim3(4, 128), blk512, 0, stream>>>(
            h1, wtE1, eb[1], nullptr, h2, h2 + (size_t)MH * 1024, MH, 2048, 1024);

        uint16_t* h3 = (uint16_t*)region1;
        gemm_256<3, true, true, 1><<<dim3(2, 128), blk512, 0, stream>>>(
            h2, wtE2, eb[2], nullptr, h3, h3 + (size_t)MH * 512, MH, 1024, 512);

        gemm_mfma<2, 2, 64, true, true, false, 0><<<dim3(2, 128), blk, 0, stream>>>(
            h3, wtE3, eb[3], z + (size_t)half * MH * 128, nullptr, nullptr, MH, 512, 128);
    }

    // ---- RQ prep (region1 now free) ----
    prep_cb2<<<2560, blk, 0, stream>>>(cb, cbh, cbl, cnorm);
    hist_kernel<<<1, blk, 0, stream>>>(labels, eoff, ecnt);
    scatter_kernel<<<128, blk, 0, stream>>>(labels, eoff, ecnt, permv);
    gather_kernel<<<8192, blk, 0, stream>>>(permv, z, resp, resph, respl);
    hipMemsetAsync((char*)d_out + LOSS_OFF * 4, 0, 4, stream);

    // ---- 4 RQ levels ----
    rq_level<false><<<522, blk, 0, stream>>>(0, eoff, permv, cb, cbh, cbl, cnorm,
        resp, resph, respl, z, out + IDX_OFF, out + XQ_OFF, out + LOSS_OFF, xqbf);
    rq_level<false><<<522, blk, 0, stream>>>(1, eoff, permv, cb, cbh, cbl, cnorm,
        resp, resph, respl, z, out + IDX_OFF, out + XQ_OFF, out + LOSS_OFF, xqbf);
    rq_level<false><<<522, blk, 0, stream>>>(2, eoff, permv, cb, cbh, cbl, cnorm,
        resp, resph, respl, z, out + IDX_OFF, out + XQ_OFF, out + LOSS_OFF, xqbf);
    rq_level<true ><<<522, blk, 0, stream>>>(3, eoff, permv, cb, cbh, cbl, cnorm,
        resp, resph, respl, z, out + IDX_OFF, out + XQ_OFF, out + LOSS_OFF, xqbf);

    // ---- decoder, bf16 (launch_bounds min-waves 4 -> 2 blocks/CU) ----
    const int M = 32768;
    uint16_t* d0 = (uint16_t*)region1;
    uint16_t* d1 = (uint16_t*)region2;
    uint16_t* d2 = (uint16_t*)region1;
    gemm_mfma<1, 3, 128, false, false, true, 2><<<dim3(4, 256), blk, 0, stream>>>(
        xqbf, wtD0, db[0], nullptr, d0, nullptr, M, 128, 512);
    gemm_256<1, false, true, 2><<<dim3(4, 256), blk512, 0, stream>>>(
        d0, wtD1, db[1], nullptr, d1, nullptr, M, 512, 1024);
    gemm_256<1, false, true, 2><<<dim3(8, 256), blk512, 0, stream>>>(
        d1, wtD2, db[2], nullptr, d2, nullptr, M, 1024, 2048);
    gemm_256<1, false, false, 0><<<dim3(3, 256), blk512, 0, stream>>>(
        d2, wtD3, db[3], out, nullptr, nullptr, M, 2048, 768);
}